// Round 15
// baseline (78.462 us; speedup 1.0000x reference)
//
#include <hip/hip_runtime.h>
#include <hip/hip_bf16.h>
#include <type_traits>

typedef __attribute__((ext_vector_type(4))) float f32x4;
typedef __attribute__((ext_vector_type(8))) short bf16x8;

static constexpr int B_   = 2048;
static constexpr int IN_  = 1024;
static constexpr int HID_ = 2048;
static constexpr int NB_  = 8;
static constexpr int BS_  = 256;   // block size
static constexpr int G3_  = 768;   // 3*BS_

// packed fp32x2 -> bf16x2 RNE, single VALU op (no builtin on gfx950)
__device__ __forceinline__ unsigned cvtpk(float lo, float hi) {
  unsigned r;
  asm("v_cvt_pk_bf16_f32 %0, %1, %2" : "=v"(r) : "v"(lo), "v"(hi));
  return r;
}

// ---------- fully-fused block-GRU MFMA kernel: 64x64 tile, 3 blocks/CU ----------
// Round-15 changes vs round 13/14 (both ~52.6):
//  * tile 64 rows x 64 out-cols, grid 1024, __launch_bounds__(256,3):
//    12 waves/CU (3/SIMD) vs 8 - the kernel is latency/lockstep-bound (all
//    pipes <25%), TLP is the lever.
//  * LDS rows PADDED to 80B (64B data + 16B pad), NO XOR swizzle: gcd(5,8)=1
//    so 8 consecutive lanes always hit 8 distinct 16B bank-groups ->
//    conflict-free by construction (both 3.3M and 3.8M XOR variants failed).
//    Possible only because staging is reg-mediated ds_write (not global_load_lds).
// LDS per buffer: A [64 rows][80B] = 5120B @0, W [192 rows][80B] = 15360B @5120;
// buffer stride 20480B, 2 buffers = 40KB.
// Staging: K32, A 1 pass + W 3 passes (32 VGPR in flight), fp32 -> cvt_pk ->
// ds_write_b128; issue-early / write-late around compute; 1 barrier per step.
// Accumulators: [0]=r (K=1280 combined), [1]=z (combined), [2]=i_n, [3]=h_n;
// wave = 32x32 out per set -> acc 64 VGPR.
__global__ __launch_bounds__(256, 3) void gru_mfma(
    const float* __restrict__ xf,     // [2048][1024]
    const float* __restrict__ hf,     // [2048][2048]
    const float* __restrict__ Wih,    // [8][768][1024]
    const float* __restrict__ Whh,    // [8][768][256]
    const float* __restrict__ b_ih,   // [8][768]
    const float* __restrict__ b_hh,   // [8][768]
    float* __restrict__ out)          // [2048][2048]
{
  __shared__ __align__(16) char lds[2][20480];

  const int t    = threadIdx.x;
  const int lane = t & 63;
  const int wid  = t >> 6;
  const int wm   = wid >> 1;     // wave row (0..1) -> 32-row half
  const int wn   = wid & 1;      // wave col (0..1) -> 32-col half

  // Bijective XCD swizzle: nwg=1024 = 8 XCDs x 128 -> each XCD owns one GRU
  // block n (ct = swz>>5 in [x*4, x*4+4) -> n = x).
  const int bid = blockIdx.x;
  const int swz = (bid & 7) * 128 + (bid >> 3);
  const int mrow0 = (swz & 31) * 64;
  const int ct    = swz >> 5;
  const int n     = ct >> 2;          // GRU block index
  const int s0    = (ct & 3) * 64;    // col offset within block

  // Staging: chunk j covers logical (row = j>>2, col16 = j&3); phys addr =
  // row*80 + (j&3)*16 (padded rows). A: j = t (1 pass). W: j = q*256 + t.
  const int ar_  = t >> 2;            // A row 0..63
  const int ac_  = (t & 3) * 8;       // A col element 0..24
  int wrow[3], wgrow[3], wcE[3];
#pragma unroll
  for (int q = 0; q < 3; ++q) {
    int j = q * 256 + t;
    wrow[q]  = j >> 2;                // 0..191
    wcE[q]   = (j & 3) * 8;
    wgrow[q] = n * G3_ + (wrow[q] >> 6) * BS_ + s0 + (wrow[q] & 63);
  }

  f32x4 acc[4][2][2] = {};   // [set][mi][ni] - 64 VGPR
  float4 sa[2];              // A staging (8 VGPR)
  float4 sw[3][2];           // W staging (24 VGPR)

  auto issue = [&](int tt) {             // 8 coalesced fp32 loads (32 VGPR)
    {
      const float* src = (tt < 32)
        ? xf + (size_t)(mrow0 + ar_) * IN_  + tt * 32 + ac_
        : hf + (size_t)(mrow0 + ar_) * HID_ + n * BS_ + (tt - 32) * 32 + ac_;
      sa[0] = *reinterpret_cast<const float4*>(src);
      sa[1] = *reinterpret_cast<const float4*>(src + 4);
    }
#pragma unroll
    for (int q = 0; q < 3; ++q) {
      const float* src = (tt < 32)
        ? Wih + (size_t)wgrow[q] * IN_ + tt * 32 + wcE[q]
        : Whh + (size_t)wgrow[q] * BS_ + (tt - 32) * 32 + wcE[q];
      sw[q][0] = *reinterpret_cast<const float4*>(src);
      sw[q][1] = *reinterpret_cast<const float4*>(src + 4);
    }
  };
  auto pack8 = [&](const float4& a, const float4& b) {
    union { unsigned u[4]; bf16x8 v; } r;
    r.u[0] = cvtpk(a.x, a.y); r.u[1] = cvtpk(a.z, a.w);
    r.u[2] = cvtpk(b.x, b.y); r.u[3] = cvtpk(b.z, b.w);
    return r.v;
  };
  auto writeAll = [&](int buf) {         // cvt + 4 ds_write_b128 (padded rows)
    char* base = (char*)lds[buf];
    *reinterpret_cast<bf16x8*>(base + ar_ * 80 + (t & 3) * 16) = pack8(sa[0], sa[1]);
#pragma unroll
    for (int q = 0; q < 3; ++q)
      *reinterpret_cast<bf16x8*>(base + 5120 + wrow[q] * 80 + ((q * 256 + t) & 3) * 16)
          = pack8(sw[q][0], sw[q][1]);
  };

  auto compute = [&](int buf, auto ph1c) {
    constexpr bool PH1 = decltype(ph1c)::value;
    const char* base = (const char*)lds[buf];
    bf16x8 af[2];
#pragma unroll
    for (int mi = 0; mi < 2; ++mi) {
      int r = wm * 32 + mi * 16 + (lane & 15);
      af[mi] = *reinterpret_cast<const bf16x8*>(base + r * 80 + ((lane >> 4) * 16));
    }
    __builtin_amdgcn_s_setprio(1);
#pragma unroll
    for (int g = 0; g < 3; ++g) {
      bf16x8 wf[2];
#pragma unroll
      for (int ni = 0; ni < 2; ++ni) {
        int wr = g * 64 + wn * 32 + ni * 16 + (lane & 15);
        wf[ni] = *reinterpret_cast<const bf16x8*>(base + 5120 + wr * 80 + ((lane >> 4) * 16));
      }
      constexpr int set2 = PH1 ? 2 : 3;
      const int set = (g < 2) ? g : set2;
#pragma unroll
      for (int mi = 0; mi < 2; ++mi)
#pragma unroll
        for (int ni = 0; ni < 2; ++ni)
          acc[set][mi][ni] = __builtin_amdgcn_mfma_f32_16x16x32_bf16(
              af[mi], wf[ni], acc[set][mi][ni], 0, 0, 0);
    }
    __builtin_amdgcn_s_setprio(0);
  };

  // ---- prologue: stage tile 0 into buf0 ----
  issue(0);
  writeAll(0);
  __syncthreads();

  // ---- 40 K-steps (32 input + 8 hidden), fully unrolled, ONE barrier each ----
#pragma unroll
  for (int tt = 0; tt < 40; ++tt) {
    const int cur = tt & 1;
    if (tt < 39) issue(tt + 1);             // T14: issue early
    __builtin_amdgcn_sched_barrier(0);      // loads stay above compute
    if (tt < 32) compute(cur, std::true_type{});
    else         compute(cur, std::false_type{});
    __builtin_amdgcn_sched_barrier(0);      // write-late boundary
    if (tt < 39) writeAll(cur ^ 1);
    __syncthreads();   // writes visible; reads of cur retired; loads consumed
  }
  // Final barrier above: K-loop LDS free -> reuse as epilogue scratch.

  // ---- epilogue: z/ng via LDS (stride-36 arrays), coalesced 128B loads/stores ----
  // Per wave: z [16][36] f32 + ng [16][36] f32 = 4608B; 4 waves = 18432B.
  // Store banks = (4*lrow + lcol) mod 32: 32 distinct per instr. Read groups =
  // (lrow + c) mod 8: distinct per 8 lanes. Two halves (mi=0,1), wave-local.
  float* ew = (float*)lds + wid * 1152;
  const int gc0 = n * BS_ + s0 + wn * 32;

#pragma unroll
  for (int mi = 0; mi < 2; ++mi) {
#pragma unroll
    for (int ni = 0; ni < 2; ++ni) {
      int scol = s0 + wn * 32 + ni * 16 + (lane & 15);
      float br_i = b_ih[n * G3_ + 0 * BS_ + scol];
      float bz_i = b_ih[n * G3_ + 1 * BS_ + scol];
      float bn_i = b_ih[n * G3_ + 2 * BS_ + scol];
      float br_h = b_hh[n * G3_ + 0 * BS_ + scol];
      float bz_h = b_hh[n * G3_ + 1 * BS_ + scol];
      float bn_h = b_hh[n * G3_ + 2 * BS_ + scol];
#pragma unroll
      for (int i = 0; i < 4; ++i) {
        float rr = acc[0][mi][ni][i] + br_i + br_h;
        float zz = acc[1][mi][ni][i] + bz_i + bz_h;
        float r  = 1.f / (1.f + __expf(-rr));
        float z  = 1.f / (1.f + __expf(-zz));
        float ng = tanhf(acc[2][mi][ni][i] + bn_i + r * (acc[3][mi][ni][i] + bn_h));
        int lrow = (lane >> 4) * 4 + i;             // 0..15 (C/D row map)
        int lcol = ni * 16 + (lane & 15);           // 0..31
        ew[lrow * 36 + lcol]       = z;
        ew[576 + lrow * 36 + lcol] = ng;
      }
    }
    asm volatile("s_waitcnt lgkmcnt(0)");
    __builtin_amdgcn_sched_barrier(0);
#pragma unroll
    for (int p = 0; p < 2; ++p) {
      int lrow = p * 8 + (lane >> 3);               // 0..15
      int grow = mrow0 + wm * 32 + mi * 16 + lrow;
      int cc   = (lane & 7) * 4;
      float4 z4  = *reinterpret_cast<const float4*>(ew + lrow * 36 + cc);
      float4 ng4 = *reinterpret_cast<const float4*>(ew + 576 + lrow * 36 + cc);
      float4 h4  = *reinterpret_cast<const float4*>(hf + (size_t)grow * HID_ + gc0 + cc);
      float4 o4;
      o4.x = (1.f - z4.x) * ng4.x + z4.x * h4.x;
      o4.y = (1.f - z4.y) * ng4.y + z4.y * h4.y;
      o4.z = (1.f - z4.z) * ng4.z + z4.z * h4.z;
      o4.w = (1.f - z4.w) * ng4.w + z4.w * h4.w;
      *reinterpret_cast<float4*>(out + (size_t)grow * HID_ + gc0 + cc) = o4;
    }
    if (mi == 0) {
      asm volatile("s_waitcnt lgkmcnt(0)");   // reads done before region reuse
      __builtin_amdgcn_sched_barrier(0);
    }
  }
}

extern "C" void kernel_launch(void* const* d_in, const int* in_sizes, int n_in,
                              void* d_out, int out_size, void* d_ws, size_t ws_size,
                              hipStream_t stream) {
  const float* x   = (const float*)d_in[0];
  const float* h   = (const float*)d_in[1];
  const float* Wih = (const float*)d_in[2];
  const float* Whh = (const float*)d_in[3];
  const float* bih = (const float*)d_in[4];
  const float* bhh = (const float*)d_in[5];
  float* out = (float*)d_out;
  (void)d_ws; (void)ws_size;

  gru_mfma<<<1024, 256, 0, stream>>>(x, h, Wih, Whh, bih, bhh, out);
}

// Round 16
// 58.934 us; speedup vs baseline: 1.3314x; 1.3314x over previous
//
#include <hip/hip_runtime.h>
#include <hip/hip_bf16.h>
#include <type_traits>

#define AS1 __attribute__((address_space(1)))
#define AS3 __attribute__((address_space(3)))

typedef __attribute__((ext_vector_type(4))) float f32x4;
typedef __attribute__((ext_vector_type(8))) short bf16x8;

template <int V> using ic = std::integral_constant<int, V>;

static constexpr int B_   = 2048;
static constexpr int IN_  = 1024;
static constexpr int HID_ = 2048;
static constexpr int NB_  = 8;
static constexpr int BS_  = 256;   // block size
static constexpr int G3_  = 768;   // 3*BS_

// ---------- fp32 -> bf16 (RNE) ----------
__device__ __forceinline__ unsigned short f2bf(float f) {
  unsigned u = __builtin_bit_cast(unsigned, f);
  u = (u + 0x7FFFu + ((u >> 16) & 1u)) >> 16;
  return (unsigned short)u;
}

__global__ void cvt_all(const float* __restrict__ x, const float* __restrict__ h,
                        const float* __restrict__ Wih, const float* __restrict__ Whh,
                        unsigned short* __restrict__ dst) {
  constexpr int c0 = (B_ * IN_) / 4;
  constexpr int c1 = c0 + (B_ * HID_) / 4;
  constexpr int c2 = c1 + (NB_ * G3_ * IN_) / 4;
  constexpr int n4 = c2 + (NB_ * G3_ * BS_) / 4;
  int i = blockIdx.x * blockDim.x + threadIdx.x;
  int stride = gridDim.x * blockDim.x;
  for (; i < n4; i += stride) {
    float4 v;
    if (i < c0)       v = reinterpret_cast<const float4*>(x)[i];
    else if (i < c1)  v = reinterpret_cast<const float4*>(h)[i - c0];
    else if (i < c2)  v = reinterpret_cast<const float4*>(Wih)[i - c1];
    else              v = reinterpret_cast<const float4*>(Whh)[i - c2];
    ushort4 o;
    o.x = f2bf(v.x); o.y = f2bf(v.y); o.z = f2bf(v.z); o.w = f2bf(v.w);
    reinterpret_cast<ushort4*>(dst)[i] = o;
  }
}

// ---------- fused block-GRU MFMA kernel: 8-wave 3-phase template (m201-style) ----------
// Tile: 128 rows x 128 out-cols (384 gate cols); 512 threads = 8 waves (2M x 4N);
// grid 256 = 1 block/CU; wave computes 64x32 per gate-set.
// Accumulators: [0]=r (K=1280 combined), [1]=z (combined), [2]=i_n, [3]=h_n.
// LDS: 2 buffers x 64KB { A [128][128B] @0, W [384][128B] @16384 }; the
// HW-verified-0-conflict layout (rounds 1-12): 128B rows, phys = logical ^
// ((row&7)<<4); global_load_lds linear dest + pre-swizzled SOURCE (rule #21).
// Per K-step, 3 phases (one gate each; 16 MFMA/wave):
//   {ds_read frags; issue staging; s_barrier; lgkmcnt(0); setprio1; MFMA; setprio0; s_barrier}
// Staging issue points (region free after its last-read phase's closing barrier):
//   P0: Wg2[t+1] (into oth)   P1: A+Wg0[t+2] (into cur)   P2: Wg1[t+2] (into cur)
// Counted wait ONCE per step at P2 tail: vmcnt(6) = t+2's 6 loads stay in
// flight; tile t+1 (its Wg2 issued at this step's P0) is guaranteed landed.
// Never vmcnt(0) in steady state (m218: counted-vs-drain0 is the whole gain).
// Biases preloaded + vmcnt(0)-fenced BEFORE staging so no stray VMEM breaks
// the vmcnt arithmetic.
__global__ __launch_bounds__(512, 2) void gru_mfma(
    const unsigned short* __restrict__ inb,    // [2048][1024] bf16
    const unsigned short* __restrict__ hidb,   // [2048][2048] bf16
    const unsigned short* __restrict__ wihb,   // [8][768][1024] bf16
    const unsigned short* __restrict__ whhb,   // [8][768][256] bf16
    const float* __restrict__ hid_f32,         // [2048][2048] fp32 (h_prev)
    const float* __restrict__ b_ih,            // [8][768]
    const float* __restrict__ b_hh,            // [8][768]
    float* __restrict__ out)                   // [2048][2048]
{
  __shared__ __align__(16) char lds[2][65536];   // per buf: A @0 (16KB), W @16384 (48KB)

  const int t    = threadIdx.x;   // 0..511
  const int lane = t & 63;
  const int wid  = t >> 6;        // 0..7
  const int wm   = wid >> 2;      // 0..1 -> 64-row half
  const int wn   = wid & 3;       // 0..3 -> 32-col quarter

  // XCD swizzle: grid 256 = 8 XCDs x 32; swz in [x*32,x*32+32) -> ct2 in
  // {2x,2x+1} -> n = x: each XCD owns exactly one GRU block (W panel L2-resident).
  const int bid = blockIdx.x;
  const int swz = (bid & 7) * 32 + (bid >> 3);
  const int mrow0 = (swz & 15) * 128;
  const int ct2   = swz >> 4;          // 0..15
  const int n     = ct2 >> 1;          // GRU block index
  const int s0    = (ct2 & 1) * 128;   // col offset within block

  // Staging pass p: phys op = p*8192 + t*16 (region-local); logical
  // ol = op ^ (((op>>7)&7)<<4) (involution on byte bits [6:4]).
  int arow[2], acb[2];
#pragma unroll
  for (int p = 0; p < 2; ++p) {
    int op = p * 8192 + t * 16;
    int ol = op ^ (((op >> 7) & 7) << 4);
    arow[p] = ol >> 7;            // 0..127
    acb[p]  = ol & 127;
  }
  int wgr[6], wcb[6];
#pragma unroll
  for (int q = 0; q < 6; ++q) {
    int op = q * 8192 + t * 16;
    int ol = op ^ (((op >> 7) & 7) << 4);
    int wr = ol >> 7;             // 0..383
    wgr[q] = n * G3_ + (wr >> 7) * BS_ + s0 + (wr & 127);  // global W row
    wcb[q] = ol & 127;
  }

  // ---- bias preload (regs), fenced so the K-loop has NO other VMEM ----
  float brz[2], bni[2], bnh[2];
#pragma unroll
  for (int ni = 0; ni < 2; ++ni) {
    int scol = s0 + wn * 32 + ni * 16 + (lane & 15);
    brz[ni] = b_ih[n * G3_ + 0 * BS_ + scol] + b_hh[n * G3_ + 0 * BS_ + scol];
    // z-gate bias folded later; store separately:
    bni[ni] = b_ih[n * G3_ + 2 * BS_ + scol];
    bnh[ni] = b_hh[n * G3_ + 2 * BS_ + scol];
  }
  float bz[2];
#pragma unroll
  for (int ni = 0; ni < 2; ++ni) {
    int scol = s0 + wn * 32 + ni * 16 + (lane & 15);
    bz[ni] = b_ih[n * G3_ + 1 * BS_ + scol] + b_hh[n * G3_ + 1 * BS_ + scol];
  }
  asm volatile("s_waitcnt vmcnt(0)");
  __builtin_amdgcn_sched_barrier(0);

  f32x4 acc[4][4][2] = {};   // [set][mi][ni]

  auto stageA = [&](int buf, int t2) {   // 2 gloadlds
    const bool ph1 = t2 < 16;
    const int ks = ph1 ? t2 : (t2 - 16);
    char* base = (char*)lds[buf];
#pragma unroll
    for (int p = 0; p < 2; ++p) {
      const char* src = ph1
        ? (const char*)inb  + ((size_t)(mrow0 + arow[p]) * IN_  + ks * 64) * 2 + acb[p]
        : (const char*)hidb + ((size_t)(mrow0 + arow[p]) * HID_ + n * BS_ + ks * 64) * 2 + acb[p];
      __builtin_amdgcn_global_load_lds((const AS1 void*)src,
                                       (AS3 void*)(base + p * 8192 + wid * 1024), 16, 0, 0);
    }
  };
  auto stageW = [&](int buf, int t2, int g) {  // 2 gloadlds (passes 2g, 2g+1)
    const bool ph1 = t2 < 16;
    const int ks = ph1 ? t2 : (t2 - 16);
    char* base = (char*)lds[buf] + 16384;
#pragma unroll
    for (int j = 0; j < 2; ++j) {
      const int q = 2 * g + j;
      const char* src = ph1
        ? (const char*)wihb + ((size_t)wgr[q] * IN_ + ks * 64) * 2 + wcb[q]
        : (const char*)whhb + ((size_t)wgr[q] * BS_ + ks * 64) * 2 + wcb[q];
      __builtin_amdgcn_global_load_lds((const AS1 void*)src,
                                       (AS3 void*)(base + q * 8192 + wid * 1024), 16, 0, 0);
    }
  };

  auto loadA = [&](int buf, bf16x8 (&af)[2][4]) {
#pragma unroll
    for (int ksub = 0; ksub < 2; ++ksub)
#pragma unroll
      for (int mi = 0; mi < 4; ++mi) {
        int ar  = wm * 64 + mi * 16 + (lane & 15);
        int off = ar * 128 + ksub * 64 + ((lane >> 4) * 16);
        off ^= (ar & 7) << 4;
        af[ksub][mi] = *reinterpret_cast<const bf16x8*>((const char*)lds[buf] + off);
      }
  };
  auto loadW = [&](int buf, int g, bf16x8 (&wf)[2][2]) {
#pragma unroll
    for (int ksub = 0; ksub < 2; ++ksub)
#pragma unroll
      for (int ni = 0; ni < 2; ++ni) {
        int wr  = g * 128 + wn * 32 + ni * 16 + (lane & 15);
        int off = wr * 128 + ksub * 64 + ((lane >> 4) * 16);
        off ^= (wr & 7) << 4;
        wf[ksub][ni] = *reinterpret_cast<const bf16x8*>((const char*)lds[buf] + 16384 + off);
      }
  };
  auto mfma16 = [&](auto setc, bf16x8 (&af)[2][4], bf16x8 (&wf)[2][2]) {
    constexpr int set = decltype(setc)::value;
    __builtin_amdgcn_s_setprio(1);
#pragma unroll
    for (int ksub = 0; ksub < 2; ++ksub)
#pragma unroll
      for (int mi = 0; mi < 4; ++mi)
#pragma unroll
        for (int ni = 0; ni < 2; ++ni)
          acc[set][mi][ni] = __builtin_amdgcn_mfma_f32_16x16x32_bf16(
              af[ksub][mi], wf[ksub][ni], acc[set][mi][ni], 0, 0, 0);
    __builtin_amdgcn_s_setprio(0);
  };

  // ---- prologue: tile0 fully; tile1 A+Wg0+Wg1 (Wg2 issues at step0 P0) ----
  stageA(0, 0); stageW(0, 0, 0); stageW(0, 0, 1); stageW(0, 0, 2);
  stageA(1, 1); stageW(1, 1, 0); stageW(1, 1, 1);
  asm volatile("s_waitcnt vmcnt(6)");    // tile0's 8 landed; tile1's 6 in flight
  __builtin_amdgcn_sched_barrier(0);
  __builtin_amdgcn_s_barrier();

  // ---- 20 K-steps (16 input + 4 hidden), fully unrolled, 3 phases each ----
#pragma unroll
  for (int tt = 0; tt < 20; ++tt) {
    const int cur = tt & 1, oth = cur ^ 1;
    bf16x8 af[2][4], wf[2][2];

    // P0: gate 0 (reads A + Wg0 of cur; issues Wg2[t+1] into oth)
    loadA(cur, af);
    loadW(cur, 0, wf);
    if (tt + 1 < 20) stageW(oth, tt + 1, 2);
    __builtin_amdgcn_s_barrier();
    asm volatile("s_waitcnt lgkmcnt(0)");
    __builtin_amdgcn_sched_barrier(0);
    mfma16(ic<0>{}, af, wf);
    __builtin_amdgcn_s_barrier();

    // P1: gate 1 (A & Wg0 of cur now free -> restage for t+2; A lives in regs)
    loadW(cur, 1, wf);
    if (tt + 2 < 20) { stageA(cur, tt + 2); stageW(cur, tt + 2, 0); }
    __builtin_amdgcn_s_barrier();
    asm volatile("s_waitcnt lgkmcnt(0)");
    __builtin_amdgcn_sched_barrier(0);
    mfma16(ic<1>{}, af, wf);
    __builtin_amdgcn_s_barrier();

    // P2: gate 2 (Wg1 of cur now free -> restage for t+2)
    loadW(cur, 2, wf);
    if (tt + 2 < 20) stageW(cur, tt + 2, 1);
    __builtin_amdgcn_s_barrier();
    asm volatile("s_waitcnt lgkmcnt(0)");
    __builtin_amdgcn_sched_barrier(0);
    if (tt < 16) mfma16(ic<2>{}, af, wf);
    else         mfma16(ic<3>{}, af, wf);
    if (tt < 18)       asm volatile("s_waitcnt vmcnt(6)");  // tile t+1 landed; t+2's 6 in flight
    else if (tt == 18) asm volatile("s_waitcnt vmcnt(0)");  // tail drain (tile 19)
    __builtin_amdgcn_sched_barrier(0);
    __builtin_amdgcn_s_barrier();
  }

  // ---- epilogue: gates + output ----
#pragma unroll
  for (int ni = 0; ni < 2; ++ni) {
    int scol = s0 + wn * 32 + ni * 16 + (lane & 15);
    int gcol = n * BS_ + scol;
#pragma unroll
    for (int mi = 0; mi < 4; ++mi) {
#pragma unroll
      for (int i = 0; i < 4; ++i) {
        int row = mrow0 + wm * 64 + mi * 16 + (lane >> 4) * 4 + i;  // C/D: col=lane&15, row=(lane>>4)*4+reg
        float hprev = hid_f32[(size_t)row * HID_ + gcol];
        float rr = acc[0][mi][ni][i] + brz[ni];
        float zz = acc[1][mi][ni][i] + bz[ni];
        float r  = 1.f / (1.f + __expf(-rr));
        float z  = 1.f / (1.f + __expf(-zz));
        float ng = tanhf(acc[2][mi][ni][i] + bni[ni] + r * (acc[3][mi][ni][i] + bnh[ni]));
        out[(size_t)row * HID_ + gcol] = (1.f - z) * ng + z * hprev;
      }
    }
  }
}

// ---------- fallback (only if ws too small): naive fp32 ----------
__global__ void gru_naive(const float* __restrict__ x, const float* __restrict__ h,
                          const float* __restrict__ Wih, const float* __restrict__ Whh,
                          const float* __restrict__ bih, const float* __restrict__ bhh,
                          float* __restrict__ out) {
  int b = blockIdx.x;
  int n = blockIdx.y;
  int s = threadIdx.x;   // 256
  __shared__ float xs[1024];
  __shared__ float hs[256];
  for (int i = threadIdx.x; i < 1024; i += 256) xs[i] = x[(size_t)b * IN_ + i];
  if (threadIdx.x < 256) hs[threadIdx.x] = h[(size_t)b * HID_ + n * BS_ + threadIdx.x];
  __syncthreads();
  float gi[3], gh[3];
  for (int g = 0; g < 3; ++g) {
    const float* w = Wih + ((size_t)(n * G3_ + g * BS_ + s)) * IN_;
    float a = 0.f;
    for (int k = 0; k < IN_; ++k) a += xs[k] * w[k];
    gi[g] = a + bih[n * G3_ + g * BS_ + s];
    const float* w2 = Whh + ((size_t)(n * G3_ + g * BS_ + s)) * BS_;
    float a2 = 0.f;
    for (int k = 0; k < BS_; ++k) a2 += hs[k] * w2[k];
    gh[g] = a2 + bhh[n * G3_ + g * BS_ + s];
  }
  float r = 1.f / (1.f + expf(-(gi[0] + gh[0])));
  float z = 1.f / (1.f + expf(-(gi[1] + gh[1])));
  float ng = tanhf(gi[2] + r * gh[2]);
  out[(size_t)b * HID_ + n * BS_ + s] = (1.f - z) * ng + z * hs[s];
}

extern "C" void kernel_launch(void* const* d_in, const int* in_sizes, int n_in,
                              void* d_out, int out_size, void* d_ws, size_t ws_size,
                              hipStream_t stream) {
  const float* x   = (const float*)d_in[0];
  const float* h   = (const float*)d_in[1];
  const float* Wih = (const float*)d_in[2];
  const float* Whh = (const float*)d_in[3];
  const float* bih = (const float*)d_in[4];
  const float* bhh = (const float*)d_in[5];
  float* out = (float*)d_out;

  const size_t szin  = (size_t)B_ * IN_;
  const size_t szhid = (size_t)B_ * HID_;
  const size_t szwih = (size_t)NB_ * G3_ * IN_;
  const size_t szwhh = (size_t)NB_ * G3_ * BS_;
  const size_t need  = (szin + szhid + szwih + szwhh) * 2;

  if (ws_size >= need) {
    unsigned short* inb  = (unsigned short*)d_ws;
    unsigned short* hidb = inb + szin;
    unsigned short* wihb = hidb + szhid;
    unsigned short* whhb = wihb + szwih;
    cvt_all<<<2048, 256, 0, stream>>>(x, h, Wih, Whh, (unsigned short*)d_ws);
    gru_mfma<<<256, 512, 0, stream>>>(inb, hidb, wihb, whhb, h, bih, bhh, out);
  } else {
    dim3 grid(B_, NB_);
    gru_naive<<<grid, 256, 0, stream>>>(x, h, Wih, Whh, bih, bhh, out);
  }
}

// Round 17
// 55.487 us; speedup vs baseline: 1.4141x; 1.0621x over previous
//
#include <hip/hip_runtime.h>
#include <hip/hip_bf16.h>
#include <type_traits>

typedef __attribute__((ext_vector_type(4))) float f32x4;
typedef __attribute__((ext_vector_type(8))) short bf16x8;

template <int V> using ic = std::integral_constant<int, V>;

static constexpr int B_   = 2048;
static constexpr int IN_  = 1024;
static constexpr int HID_ = 2048;
static constexpr int NB_  = 8;
static constexpr int BS_  = 256;   // block size
static constexpr int G3_  = 768;   // 3*BS_

// packed fp32x2 -> bf16x2 RNE, single VALU op (no builtin on gfx950)
__device__ __forceinline__ unsigned cvtpk(float lo, float hi) {
  unsigned r;
  asm("v_cvt_pk_bf16_f32 %0, %1, %2" : "=v"(r) : "v"(lo), "v"(hi));
  return r;
}

// ---------- fully-fused block-GRU MFMA kernel: K64, 8-wave, proven layout ----------
// Single launch, no workspace. Tile 128 rows x 128 out-cols (384 gate cols);
// 512 threads = 8 waves (2M x 4N); wave computes 64x32 per gate-set; grid 256
// = 1 block/CU. XCD-bijective swizzle: each XCD owns one GRU block n -> its
// fp32 W panel (3.9MB) is L2-resident.
// Accumulators: [0]=r (K=1280 combined), [1]=z (combined), [2]=i_n, [3]=h_n.
// LDS: 2 buffers x 64KB { A [128 rows][128B] @0, W [384 rows][128B] @16384 }.
// Layout = the ONLY HW-verified-0-conflict one (rounds 1-12 K-loop, rounds 7/8
// ds_write staging): 128B rows, phys = logical ^ ((row&7)<<4). Full-row writes
// (j&7 spans all 8 bank-groups) require K-step 64 - K32's 64B rows are
// structurally conflicted (rounds 13-15).
// Staging: fp32 -> v_cvt_pk_bf16_f32 -> ds_write_b128, TWO 32-VGPR batches
// sharing one buffer (round-8's spill fixed): B1 = A p0,p1 + W q0,q1 issued at
// step head, written after gate-0's MFMAs; B2 = W q2..q5 issued there, written
// after gate-2. One __syncthreads per step; NO manual vmcnt (compiler inserts
// counted waits - minimal race surface).
__global__ __launch_bounds__(512, 2) void gru_mfma(
    const float* __restrict__ xf,     // [2048][1024]
    const float* __restrict__ hf,     // [2048][2048]
    const float* __restrict__ Wih,    // [8][768][1024]
    const float* __restrict__ Whh,    // [8][768][256]
    const float* __restrict__ b_ih,   // [8][768]
    const float* __restrict__ b_hh,   // [8][768]
    float* __restrict__ out)          // [2048][2048]
{
  __shared__ __align__(16) char lds[2][65536];

  const int t    = threadIdx.x;   // 0..511
  const int lane = t & 63;
  const int wid  = t >> 6;        // 0..7
  const int wm   = wid >> 2;      // 0..1 -> 64-row half
  const int wn   = wid & 3;       // 0..3 -> 32-col quarter

  // XCD swizzle: grid 256 = 8 XCDs x 32; ct2 = swz>>4 in {2x,2x+1} -> n = x.
  const int bid = blockIdx.x;
  const int swz = (bid & 7) * 32 + (bid >> 3);
  const int mrow0 = (swz & 15) * 128;
  const int ct2   = swz >> 4;          // 0..15
  const int n     = ct2 >> 1;          // GRU block index
  const int s0    = (ct2 & 1) * 128;   // col offset within block (0 or 128)

  // Staging pass p: phys op = p*8192 + t*16 (region-local, 512 thr x 16B = half
  // region... A region 16KB = 2 passes; W region 48KB = 6 passes).
  // Logical ol = op ^ (((op>>7)&7)<<4) (involution on byte bits [6:4]).
  int arow[2], acolE[2];
#pragma unroll
  for (int p = 0; p < 2; ++p) {
    int op = p * 8192 + t * 16;
    int ol = op ^ (((op >> 7) & 7) << 4);
    arow[p]  = ol >> 7;            // 0..127
    acolE[p] = (ol & 127) >> 1;    // bf16-element offset {0,8,..,56}
  }
  int wgr[6], wcolE[6];
#pragma unroll
  for (int q = 0; q < 6; ++q) {
    int op = q * 8192 + t * 16;
    int ol = op ^ (((op >> 7) & 7) << 4);
    int wr = ol >> 7;              // 0..383
    wgr[q]   = n * G3_ + (wr >> 7) * BS_ + s0 + (wr & 127);  // global W row
    wcolE[q] = (ol & 127) >> 1;
  }

  f32x4 acc[4][4][2] = {};   // [set][mi][ni] - 128 regs (AGPR side)
  float4 s[4][2];            // staging buffer: 4 passes x 8 fp32 = 32 VGPR

  auto issueB1 = [&](int tt) {   // A p0,p1 -> s[0],s[1]; W q0,q1 -> s[2],s[3]
#pragma unroll
    for (int p = 0; p < 2; ++p) {
      const float* src = (tt < 16)
        ? xf + (size_t)(mrow0 + arow[p]) * IN_  + tt * 64 + acolE[p]
        : hf + (size_t)(mrow0 + arow[p]) * HID_ + n * BS_ + (tt - 16) * 64 + acolE[p];
      s[p][0] = *reinterpret_cast<const float4*>(src);
      s[p][1] = *reinterpret_cast<const float4*>(src + 4);
    }
#pragma unroll
    for (int q = 0; q < 2; ++q) {
      const float* src = (tt < 16)
        ? Wih + (size_t)wgr[q] * IN_ + tt * 64 + wcolE[q]
        : Whh + (size_t)wgr[q] * BS_ + (tt - 16) * 64 + wcolE[q];
      s[2 + q][0] = *reinterpret_cast<const float4*>(src);
      s[2 + q][1] = *reinterpret_cast<const float4*>(src + 4);
    }
  };
  auto issueB2 = [&](int tt) {   // W q2..q5 -> s[0..3]
#pragma unroll
    for (int j = 0; j < 4; ++j) {
      const int q = 2 + j;
      const float* src = (tt < 16)
        ? Wih + (size_t)wgr[q] * IN_ + tt * 64 + wcolE[q]
        : Whh + (size_t)wgr[q] * BS_ + (tt - 16) * 64 + wcolE[q];
      s[j][0] = *reinterpret_cast<const float4*>(src);
      s[j][1] = *reinterpret_cast<const float4*>(src + 4);
    }
  };
  auto pack8 = [&](const float4& a, const float4& b) {
    union { unsigned u[4]; bf16x8 v; } r;
    r.u[0] = cvtpk(a.x, a.y); r.u[1] = cvtpk(a.z, a.w);
    r.u[2] = cvtpk(b.x, b.y); r.u[3] = cvtpk(b.z, b.w);
    return r.v;
  };
  auto writeB1 = [&](int buf) {
    char* base = (char*)lds[buf];
#pragma unroll
    for (int p = 0; p < 2; ++p)
      *reinterpret_cast<bf16x8*>(base + p * 8192 + t * 16) = pack8(s[p][0], s[p][1]);
#pragma unroll
    for (int q = 0; q < 2; ++q)
      *reinterpret_cast<bf16x8*>(base + 16384 + q * 8192 + t * 16) = pack8(s[2 + q][0], s[2 + q][1]);
  };
  auto writeB2 = [&](int buf) {
    char* base = (char*)lds[buf] + 16384;
#pragma unroll
    for (int j = 0; j < 4; ++j)
      *reinterpret_cast<bf16x8*>(base + (2 + j) * 8192 + t * 16) = pack8(s[j][0], s[j][1]);
  };

  auto loadA = [&](int buf, bf16x8 (&af)[2][4]) {
#pragma unroll
    for (int ksub = 0; ksub < 2; ++ksub)
#pragma unroll
      for (int mi = 0; mi < 4; ++mi) {
        int ar  = wm * 64 + mi * 16 + (lane & 15);
        int off = ar * 128 + ksub * 64 + ((lane >> 4) * 16);
        off ^= (ar & 7) << 4;
        af[ksub][mi] = *reinterpret_cast<const bf16x8*>((const char*)lds[buf] + off);
      }
  };
  auto gate = [&](int buf, int g, auto setc, bf16x8 (&af)[2][4]) {
    constexpr int set = decltype(setc)::value;
#pragma unroll
    for (int ksub = 0; ksub < 2; ++ksub) {
      bf16x8 wf[2];
#pragma unroll
      for (int ni = 0; ni < 2; ++ni) {
        int wr  = g * 128 + wn * 32 + ni * 16 + (lane & 15);
        int off = wr * 128 + ksub * 64 + ((lane >> 4) * 16);
        off ^= (wr & 7) << 4;
        wf[ni] = *reinterpret_cast<const bf16x8*>((const char*)lds[buf] + 16384 + off);
      }
      __builtin_amdgcn_s_setprio(1);
#pragma unroll
      for (int mi = 0; mi < 4; ++mi)
#pragma unroll
        for (int ni = 0; ni < 2; ++ni)
          acc[set][mi][ni] = __builtin_amdgcn_mfma_f32_16x16x32_bf16(
              af[ksub][mi], wf[ni], acc[set][mi][ni], 0, 0, 0);
      __builtin_amdgcn_s_setprio(0);
    }
  };

  // ---- prologue: stage tile 0 into buf0 ----
  issueB1(0); writeB1(0);
  issueB2(0); writeB2(0);
  __syncthreads();

  // ---- 20 K-steps (16 input + 4 hidden), fully unrolled, ONE barrier each ----
#pragma unroll
  for (int tt = 0; tt < 20; ++tt) {
    const int cur = tt & 1, oth = cur ^ 1;
    bf16x8 af[2][4];

    if (tt < 19) issueB1(tt + 1);           // T14: issue early
    __builtin_amdgcn_sched_barrier(0);
    loadA(cur, af);
    gate(cur, 0, ic<0>{}, af);              // gate 0 (16 MFMAs) hides B1 latency
    __builtin_amdgcn_sched_barrier(0);
    if (tt < 19) { writeB1(oth); issueB2(tt + 1); }
    __builtin_amdgcn_sched_barrier(0);
    gate(cur, 1, ic<1>{}, af);              // gates 1+2 (32 MFMAs) hide B2
    if (tt < 16) gate(cur, 2, ic<2>{}, af);
    else         gate(cur, 2, ic<3>{}, af);
    __builtin_amdgcn_sched_barrier(0);
    if (tt < 19) writeB2(oth);
    __syncthreads();   // writes visible; reads of cur retired; loads consumed
  }
  // Final barrier: K-loop LDS free -> reuse as epilogue scratch.

  // ---- epilogue: z/ng via LDS (stride-36), coalesced 128B hprev/out ----
  // Per wave: z[16][36] + ng[16][36] f32 = 4608B; 8 waves = 36864B. 4 rounds
  // (mi = 0..3, 16 rows each). Wave-local; lgkmcnt fences only.
  float* ew = (float*)lds + wid * 1152;
  const int gc0 = n * BS_ + s0 + wn * 32;

#pragma unroll
  for (int mi = 0; mi < 4; ++mi) {
#pragma unroll
    for (int ni = 0; ni < 2; ++ni) {
      int scol = s0 + wn * 32 + ni * 16 + (lane & 15);
      float br = b_ih[n * G3_ + 0 * BS_ + scol] + b_hh[n * G3_ + 0 * BS_ + scol];
      float bzv = b_ih[n * G3_ + 1 * BS_ + scol] + b_hh[n * G3_ + 1 * BS_ + scol];
      float bni = b_ih[n * G3_ + 2 * BS_ + scol];
      float bnh = b_hh[n * G3_ + 2 * BS_ + scol];
#pragma unroll
      for (int i = 0; i < 4; ++i) {
        float rr = acc[0][mi][ni][i] + br;
        float zz = acc[1][mi][ni][i] + bzv;
        float r  = 1.f / (1.f + __expf(-rr));
        float z  = 1.f / (1.f + __expf(-zz));
        float ng = tanhf(acc[2][mi][ni][i] + bni + r * (acc[3][mi][ni][i] + bnh));
        int lrow = (lane >> 4) * 4 + i;             // 0..15 (C/D row map)
        int lcol = ni * 16 + (lane & 15);           // 0..31
        ew[lrow * 36 + lcol]       = z;
        ew[576 + lrow * 36 + lcol] = ng;
      }
    }
    asm volatile("s_waitcnt lgkmcnt(0)");
    __builtin_amdgcn_sched_barrier(0);
#pragma unroll
    for (int p = 0; p < 2; ++p) {
      int lrow = p * 8 + (lane >> 3);               // 0..15
      int grow = mrow0 + wm * 64 + mi * 16 + lrow;
      int cc   = (lane & 7) * 4;
      float4 z4  = *reinterpret_cast<const float4*>(ew + lrow * 36 + cc);
      float4 ng4 = *reinterpret_cast<const float4*>(ew + 576 + lrow * 36 + cc);
      float4 h4  = *reinterpret_cast<const float4*>(hf + (size_t)grow * HID_ + gc0 + cc);
      float4 o4;
      o4.x = (1.f - z4.x) * ng4.x + z4.x * h4.x;
      o4.y = (1.f - z4.y) * ng4.y + z4.y * h4.y;
      o4.z = (1.f - z4.z) * ng4.z + z4.z * h4.z;
      o4.w = (1.f - z4.w) * ng4.w + z4.w * h4.w;
      *reinterpret_cast<float4*>(out + (size_t)grow * HID_ + gc0 + cc) = o4;
    }
    if (mi < 3) {
      asm volatile("s_waitcnt lgkmcnt(0)");   // reads done before region reuse
      __builtin_amdgcn_sched_barrier(0);
    }
  }
}

extern "C" void kernel_launch(void* const* d_in, const int* in_sizes, int n_in,
                              void* d_out, int out_size, void* d_ws, size_t ws_size,
                              hipStream_t stream) {
  const float* x   = (const float*)d_in[0];
  const float* h   = (const float*)d_in[1];
  const float* Wih = (const float*)d_in[2];
  const float* Whh = (const float*)d_in[3];
  const float* bih = (const float*)d_in[4];
  const float* bhh = (const float*)d_in[5];
  float* out = (float*)d_out;
  (void)d_ws; (void)ws_size;

  gru_mfma<<<256, 512, 0, stream>>>(x, h, Wih, Whh, bih, bhh, out);
}

// Round 18
// 52.569 us; speedup vs baseline: 1.4926x; 1.0555x over previous
//
#include <hip/hip_runtime.h>
#include <hip/hip_bf16.h>
#include <type_traits>

typedef __attribute__((ext_vector_type(4))) float f32x4;
typedef __attribute__((ext_vector_type(8))) short bf16x8;

template <int V> using ic = std::integral_constant<int, V>;

static constexpr int B_   = 2048;
static constexpr int IN_  = 1024;
static constexpr int HID_ = 2048;
static constexpr int NB_  = 8;
static constexpr int BS_  = 256;   // block size
static constexpr int G3_  = 768;   // 3*BS_

// packed fp32x2 -> bf16x2 RNE, single VALU op (no builtin on gfx950)
__device__ __forceinline__ unsigned cvtpk(float lo, float hi) {
  unsigned r;
  asm("v_cvt_pk_bf16_f32 %0, %1, %2" : "=v"(r) : "v"(lo), "v"(hi));
  return r;
}

// ---------- fully-fused block-GRU MFMA kernel, K-step 32 (BEST: 52.6 us) ----------
// Final submission = round-13 configuration (best of 17 measured variants).
// Single launch, no workspace: fp32->bf16 conversion rides inside staging.
// Tile: 128 batch rows x 64 out-cols (192 gate cols); 4 waves (2x2), wave 64x32.
// Accumulators: [0]=r (K=1280 combined), [1]=z (combined), [2]=i_n, [3]=h_n.
// LDS: 2 buffers x 20KB { A [128][32]bf16 @0, W [192][32]bf16 @8192 }.
// Staging: K32 => 5 passes (A2+W3, 40 VGPR in flight, ONE batch -> no spill):
// issue 10 fp32 loads at step top -> compute (24 MFMAs) hides latency ->
// cvt_pk + 5 ds_write_b128 at tail -> __syncthreads.
// XCD-bijective swizzle: each XCD owns one GRU block n (W panel L2-resident).
__global__ __launch_bounds__(256, 2) void gru_mfma(
    const float* __restrict__ xf,     // [2048][1024]
    const float* __restrict__ hf,     // [2048][2048]
    const float* __restrict__ Wih,    // [8][768][1024]
    const float* __restrict__ Whh,    // [8][768][256]
    const float* __restrict__ b_ih,   // [8][768]
    const float* __restrict__ b_hh,   // [8][768]
    float* __restrict__ out)          // [2048][2048]
{
  __shared__ __align__(16) char lds[2][20480];

  const int t    = threadIdx.x;
  const int lane = t & 63;
  const int wid  = t >> 6;
  const int wm   = wid >> 1;     // wave row (0..1) -> 64-row half
  const int wn   = wid & 1;      // wave col (0..1) -> 32-col half

  // Bijective XCD swizzle: nwg=512 = 8 XCDs x 64 -> each XCD owns one GRU block n.
  const int bid = blockIdx.x;
  const int swz = (bid & 7) * 64 + (bid >> 3);
  const int mrow0 = (swz & 15) * 128;
  const int ct    = swz >> 4;
  const int n     = ct >> 2;          // GRU block index
  const int s0    = (ct & 3) * 64;    // col offset within block

  // Staging pass p targets phys offset op = p*4096 + t*16 (region-local);
  // the element that belongs there is logical ol = op ^ (((op>>6)&3)<<4)
  // (involution on byte bits [5:4] keyed by row bits [7:6]).
  int arow[2], acolE[2];
#pragma unroll
  for (int p = 0; p < 2; ++p) {
    int op = p * 4096 + t * 16;
    int ol = op ^ (((op >> 6) & 3) << 4);
    arow[p]  = ol >> 6;           // 0..127
    acolE[p] = (ol & 63) >> 1;    // element offset {0,8,16,24}
  }
  int wgrow[3], wcolE[3];
#pragma unroll
  for (int q = 0; q < 3; ++q) {
    int op = q * 4096 + t * 16;
    int ol = op ^ (((op >> 6) & 3) << 4);
    int wr = ol >> 6;             // 0..191
    wgrow[q]  = n * G3_ + (wr >> 6) * BS_ + s0 + (wr & 63);  // global W row
    wcolE[q]  = (ol & 63) >> 1;
  }

  f32x4 acc[4][4][2] = {};   // [set][mi][ni]
  float4 sa[2][2];           // A staging (16 VGPR)
  float4 sw[3][2];           // W staging (24 VGPR)

  auto issue = [&](int tt) {             // 10 coalesced fp32 loads (40 VGPR)
#pragma unroll
    for (int p = 0; p < 2; ++p) {
      const float* src = (tt < 32)
        ? xf + (size_t)(mrow0 + arow[p]) * IN_  + tt * 32 + acolE[p]
        : hf + (size_t)(mrow0 + arow[p]) * HID_ + n * BS_ + (tt - 32) * 32 + acolE[p];
      sa[p][0] = *reinterpret_cast<const float4*>(src);
      sa[p][1] = *reinterpret_cast<const float4*>(src + 4);
    }
#pragma unroll
    for (int q = 0; q < 3; ++q) {
      const float* src = (tt < 32)
        ? Wih + (size_t)wgrow[q] * IN_ + tt * 32 + wcolE[q]
        : Whh + (size_t)wgrow[q] * BS_ + (tt - 32) * 32 + wcolE[q];
      sw[q][0] = *reinterpret_cast<const float4*>(src);
      sw[q][1] = *reinterpret_cast<const float4*>(src + 4);
    }
  };
  auto pack8 = [&](const float4& a, const float4& b) {
    union { unsigned u[4]; bf16x8 v; } r;
    r.u[0] = cvtpk(a.x, a.y); r.u[1] = cvtpk(a.z, a.w);
    r.u[2] = cvtpk(b.x, b.y); r.u[3] = cvtpk(b.z, b.w);
    return r.v;
  };
  auto writeAll = [&](int buf) {         // cvt + 5 ds_write_b128 (linear phys)
    char* base = (char*)lds[buf];
#pragma unroll
    for (int p = 0; p < 2; ++p)
      *reinterpret_cast<bf16x8*>(base + p * 4096 + t * 16) = pack8(sa[p][0], sa[p][1]);
#pragma unroll
    for (int q = 0; q < 3; ++q)
      *reinterpret_cast<bf16x8*>(base + 8192 + q * 4096 + t * 16) = pack8(sw[q][0], sw[q][1]);
  };

  auto compute = [&](int buf, auto ph1c) {
    constexpr bool PH1 = decltype(ph1c)::value;
    const char* base = (const char*)lds[buf];
    bf16x8 af[4];
#pragma unroll
    for (int mi = 0; mi < 4; ++mi) {
      int ar  = wm * 64 + mi * 16 + (lane & 15);
      int off = (ar * 64 + ((lane >> 4) * 16)) ^ ((ar & 3) << 4);
      af[mi] = *reinterpret_cast<const bf16x8*>(base + off);
    }
    __builtin_amdgcn_s_setprio(1);
#pragma unroll
    for (int g = 0; g < 3; ++g) {
      bf16x8 wf[2];
#pragma unroll
      for (int ni = 0; ni < 2; ++ni) {
        int wr  = g * 64 + wn * 32 + ni * 16 + (lane & 15);
        int off = (wr * 64 + ((lane >> 4) * 16)) ^ ((wr & 3) << 4);
        wf[ni] = *reinterpret_cast<const bf16x8*>(base + 8192 + off);
      }
      constexpr int set2 = PH1 ? 2 : 3;
      const int set = (g < 2) ? g : set2;
#pragma unroll
      for (int mi = 0; mi < 4; ++mi)
#pragma unroll
        for (int ni = 0; ni < 2; ++ni)
          acc[set][mi][ni] = __builtin_amdgcn_mfma_f32_16x16x32_bf16(
              af[mi], wf[ni], acc[set][mi][ni], 0, 0, 0);
    }
    __builtin_amdgcn_s_setprio(0);
  };

  // ---- prologue: stage tile 0 into buf0 ----
  issue(0);
  writeAll(0);
  __syncthreads();

  // ---- 40 K-steps (32 input + 8 hidden), fully unrolled, ONE barrier each ----
#pragma unroll
  for (int tt = 0; tt < 40; ++tt) {
    const int cur = tt & 1;

    if (tt < 39) issue(tt + 1);             // T14: issue early
    __builtin_amdgcn_sched_barrier(0);      // loads stay above compute
    if (tt < 32) compute(cur, std::true_type{});
    else         compute(cur, std::false_type{});
    __builtin_amdgcn_sched_barrier(0);      // write-late boundary
    if (tt < 39) writeAll(cur ^ 1);
    __syncthreads();   // writes visible; reads of cur retired; loads consumed
  }

  // ---- epilogue: gates + output ----
#pragma unroll
  for (int ni = 0; ni < 2; ++ni) {
    int scol = s0 + wn * 32 + ni * 16 + (lane & 15);
    float br_i = b_ih[n * G3_ + 0 * BS_ + scol];
    float bz_i = b_ih[n * G3_ + 1 * BS_ + scol];
    float bn_i = b_ih[n * G3_ + 2 * BS_ + scol];
    float br_h = b_hh[n * G3_ + 0 * BS_ + scol];
    float bz_h = b_hh[n * G3_ + 1 * BS_ + scol];
    float bn_h = b_hh[n * G3_ + 2 * BS_ + scol];
    int gcol = n * BS_ + scol;
#pragma unroll
    for (int mi = 0; mi < 4; ++mi) {
#pragma unroll
      for (int i = 0; i < 4; ++i) {
        int row = mrow0 + wm * 64 + mi * 16 + (lane >> 4) * 4 + i;  // C/D: col=lane&15, row=(lane>>4)*4+reg
        float hprev = hf[(size_t)row * HID_ + gcol];
        float rr = acc[0][mi][ni][i] + br_i + br_h;
        float zz = acc[1][mi][ni][i] + bz_i + bz_h;
        float r  = 1.f / (1.f + __expf(-rr));
        float z  = 1.f / (1.f + __expf(-zz));
        float ng = tanhf(acc[2][mi][ni][i] + bn_i + r * (acc[3][mi][ni][i] + bn_h));
        out[(size_t)row * HID_ + gcol] = (1.f - z) * ng + z * hprev;
      }
    }
  }
}

extern "C" void kernel_launch(void* const* d_in, const int* in_sizes, int n_in,
                              void* d_out, int out_size, void* d_ws, size_t ws_size,
                              hipStream_t stream) {
  const float* x   = (const float*)d_in[0];
  const float* h   = (const float*)d_in[1];
  const float* Wih = (const float*)d_in[2];
  const float* Whh = (const float*)d_in[3];
  const float* bih = (const float*)d_in[4];
  const float* bhh = (const float*)d_in[5];
  float* out = (float*)d_out;
  (void)d_ws; (void)ws_size;

  gru_mfma<<<512, 256, 0, stream>>>(x, h, Wih, Whh, bih, bhh, out);
}